// Round 3
// baseline (720.315 us; speedup 1.0000x reference)
//
#include <hip/hip_runtime.h>
#include <hip/hip_bf16.h>

#define BB 8192
#define MM 64
#define DD 256
#define NEGV -1e9f
#define PSTR 68   // part[] row stride in floats (68: 4-way max on b128 reads)

typedef __attribute__((ext_vector_type(8))) short frag_ab;  // 8 bf16 = 4 VGPRs
typedef __attribute__((ext_vector_type(4))) float f32x4;

__device__ inline short f2bs(float f) {
    __hip_bfloat16 v = __float2bfloat16(f);
    return *reinterpret_cast<short*>(&v);
}
// unpack packed bf16x2 word -> fp32 (1 VALU each)
__device__ inline float blo(unsigned w) { return __uint_as_float(w << 16); }
__device__ inline float bhi(unsigned w) { return __uint_as_float(w & 0xffff0000u); }

// ---------------------------------------------------------------------------
// Kernel A v3: per-sample masked attention. One block (4 waves) per sample.
//   - coalesced loads: wave w owns rows 16w..16w+15, lane owns cols 4L..4L+3
//     (each dwordx4 instr = contiguous 1KB row segment, lines fully consumed)
//   - mem tile lives in REGISTERS as bf16x2 (32 VGPRs) -> no 33KB LDS tile,
//     occupancy 6 blocks/CU instead of 4
//   - score reduce: lane partials through small LDS + 2 DPP quad shuffles
//   - r-pass: register FMA per wave, cross-wave sum via 4KB LDS
// ---------------------------------------------------------------------------
__global__ __launch_bounds__(256, 6) void attn_kernel(
    const float* __restrict__ h, const float* __restrict__ mem,
    const int* __restrict__ len, float* __restrict__ r_out)
{
    __shared__ float part[MM * PSTR];              // 17.4 KB [m][lane] partials
    __shared__ float score_s[MM];
    __shared__ __align__(16) float attn_s[MM];
    __shared__ __align__(16) float rpart[4 * DD];  // 4 KB [wave][d]

    const int b    = blockIdx.x;
    const int t    = threadIdx.x;
    const int lane = t & 63;
    const int wave = t >> 6;
    const int L    = len[b];

    // h chunk for this lane's columns (same line across waves -> L1 hit)
    const float4 hv = *reinterpret_cast<const float4*>(h + (size_t)b * DD + 4 * lane);
    const float* mbase = mem + (size_t)b * MM * DD + (size_t)(wave * 16) * DD + 4 * lane;

    // ---- phase 1: load 16 rows (coalesced), keep bf16x2 tile in registers,
    //      accumulate per-row lane partials
    unsigned tile[32];
    float p[16];
    #pragma unroll
    for (int i = 0; i < 16; ++i) {
        const float4 v = *reinterpret_cast<const float4*>(mbase + i * DD);
        p[i] = v.x * hv.x + v.y * hv.y + v.z * hv.z + v.w * hv.w;
        __hip_bfloat162 q0 = __float22bfloat162_rn(float2{v.x, v.y});
        __hip_bfloat162 q1 = __float22bfloat162_rn(float2{v.z, v.w});
        tile[2 * i]     = *reinterpret_cast<unsigned*>(&q0);
        tile[2 * i + 1] = *reinterpret_cast<unsigned*>(&q1);
    }
    #pragma unroll
    for (int i = 0; i < 16; ++i)
        part[(wave * 16 + i) * PSTR + lane] = p[i];   // b32, conflict-free
    __syncthreads();

    // ---- phase 2: finish the 64-lane dot: thread -> row m=t>>2, chunk c=t&3
    {
        const int m = t >> 2, c = t & 3;
        const float4* pr = reinterpret_cast<const float4*>(part + m * PSTR + c * 16);
        const float4 s0 = pr[0], s1 = pr[1], s2 = pr[2], s3 = pr[3];
        float s = (s0.x + s0.y + s0.z + s0.w) + (s1.x + s1.y + s1.z + s1.w)
                + (s2.x + s2.y + s2.z + s2.w) + (s3.x + s3.y + s3.z + s3.w);
        s += __shfl_xor(s, 1, 64);   // quad-perm DPP (VALU pipe)
        s += __shfl_xor(s, 2, 64);
        if (c == 0) score_s[m] = (m < L) ? s : NEGV;
    }
    __syncthreads();

    // ---- phase 3: masked softmax over 64 scores (wave 0)
    // L==0: uniform attn (harmless; gate kernel passes h through)
    if (t < 64) {
        const float s = score_s[t];
        float mx = s;
        #pragma unroll
        for (int off = 32; off > 0; off >>= 1)
            mx = fmaxf(mx, __shfl_xor(mx, off, 64));
        const float e = __expf(s - mx);
        float den = e;
        #pragma unroll
        for (int off = 32; off > 0; off >>= 1)
            den += __shfl_xor(den, off, 64);
        attn_s[t] = e / den;
    }
    __syncthreads();

    // ---- phase 4: r partials from the register tile
    float4 rp = {0.f, 0.f, 0.f, 0.f};
    #pragma unroll
    for (int ic = 0; ic < 4; ++ic) {
        const float4 aw = *reinterpret_cast<const float4*>(attn_s + wave * 16 + 4 * ic); // broadcast
        const float a[4] = {aw.x, aw.y, aw.z, aw.w};
        #pragma unroll
        for (int k = 0; k < 4; ++k) {
            const int i = 4 * ic + k;
            rp.x += a[k] * blo(tile[2 * i]);
            rp.y += a[k] * bhi(tile[2 * i]);
            rp.z += a[k] * blo(tile[2 * i + 1]);
            rp.w += a[k] * bhi(tile[2 * i + 1]);
        }
    }
    *reinterpret_cast<float4*>(rpart + wave * DD + 4 * lane) = rp;  // b128, conflict-free
    __syncthreads();

    // ---- phase 5: cross-wave sum + store (coalesced)
    const float r = rpart[t] + rpart[DD + t] + rpart[2 * DD + t] + rpart[3 * DD + t];
    r_out[(size_t)b * DD + t] = r;
}

// ---------------------------------------------------------------------------
// Kernel B (unchanged from R2): gating GEMMs + blend via bf16 MFMA 16x16x32.
// ---------------------------------------------------------------------------
__global__ __launch_bounds__(256) void gate_kernel(
    const float* __restrict__ h, const float* __restrict__ r,
    const int* __restrict__ len,
    const float* __restrict__ Wg_w, const float* __restrict__ Wg_b,
    const float* __restrict__ Ug_w, const float* __restrict__ Ug_b,
    const float* __restrict__ b_g, float* __restrict__ out)
{
    __shared__ __hip_bfloat16 Abuf[64 * 32];   // 4 KB
    __shared__ __hip_bfloat16 Wbuf[64 * 32];   // 4 KB

    const int t    = threadIdx.x;
    const int lane = t & 63;
    const int wave = t >> 6;
    const int brow0 = blockIdx.x * 64;
    const int dcol0 = blockIdx.y * 64;

    const int srow = t >> 2;     // staging row 0..63
    const int skq  = t & 3;      // staging k-octet

    const f32x4 zero = {0.f, 0.f, 0.f, 0.f};
    f32x4 acc[4];
    #pragma unroll
    for (int ct = 0; ct < 4; ++ct) acc[ct] = zero;

    const int arow_m = (lane & 15);          // MFMA A row within 16-tile
    const int kchunk = (lane >> 4) * 8;      // MFMA k-octet within BK=32

    for (int phase = 0; phase < 2; ++phase) {
        const float* Ag = phase ? r : h;
        const float* Wg = phase ? Ug_w : Wg_w;
        const float* ap = Ag + (size_t)(brow0 + srow) * DD + skq * 8;
        const float* wp = Wg + (size_t)(dcol0 + srow) * DD + skq * 8;

        for (int k0 = 0; k0 < DD; k0 += 32) {
            const float4 a0 = *reinterpret_cast<const float4*>(ap + k0);
            const float4 a1 = *reinterpret_cast<const float4*>(ap + k0 + 4);
            const float4 w0 = *reinterpret_cast<const float4*>(wp + k0);
            const float4 w1 = *reinterpret_cast<const float4*>(wp + k0 + 4);

            __syncthreads();   // previous step's frags fully read
            frag_ab av, wv;
            av[0] = f2bs(a0.x); av[1] = f2bs(a0.y); av[2] = f2bs(a0.z); av[3] = f2bs(a0.w);
            av[4] = f2bs(a1.x); av[5] = f2bs(a1.y); av[6] = f2bs(a1.z); av[7] = f2bs(a1.w);
            wv[0] = f2bs(w0.x); wv[1] = f2bs(w0.y); wv[2] = f2bs(w0.z); wv[3] = f2bs(w0.w);
            wv[4] = f2bs(w1.x); wv[5] = f2bs(w1.y); wv[6] = f2bs(w1.z); wv[7] = f2bs(w1.w);
            *reinterpret_cast<frag_ab*>(&Abuf[srow * 32 + skq * 8]) = av;
            *reinterpret_cast<frag_ab*>(&Wbuf[srow * 32 + skq * 8]) = wv;
            __syncthreads();

            const frag_ab af = *reinterpret_cast<const frag_ab*>(
                &Abuf[(wave * 16 + arow_m) * 32 + kchunk]);
            #pragma unroll
            for (int ct = 0; ct < 4; ++ct) {
                const frag_ab wf = *reinterpret_cast<const frag_ab*>(
                    &Wbuf[(ct * 16 + arow_m) * 32 + kchunk]);
                acc[ct] = __builtin_amdgcn_mfma_f32_16x16x32_bf16(af, wf, acc[ct], 0, 0, 0);
            }
        }
    }

    // epilogue: bias + sigmoid + blend + empty-memory passthrough
    // C/D layout: col = lane&15, row = (lane>>4)*4 + reg
    float bias_v[4];
    #pragma unroll
    for (int ct = 0; ct < 4; ++ct) {
        const int d = dcol0 + ct * 16 + (lane & 15);
        bias_v[ct] = Wg_b[d] + Ug_b[d] + b_g[d];
    }
    const int rbase = brow0 + wave * 16 + (lane >> 4) * 4;
    #pragma unroll
    for (int i = 0; i < 4; ++i) {
        const int bb = rbase + i;
        const int lb = len[bb];
        #pragma unroll
        for (int ct = 0; ct < 4; ++ct) {
            const int d = dcol0 + ct * 16 + (lane & 15);
            const float x = acc[ct][i] + bias_v[ct];
            const float g = 1.f / (1.f + __expf(-x));
            const size_t idx = (size_t)bb * DD + d;
            const float rv = r[idx];
            const float hvv = h[idx];
            out[idx] = (lb > 0) ? (hvv + g * (rv - hvv)) : hvv;
        }
    }
}

extern "C" void kernel_launch(void* const* d_in, const int* in_sizes, int n_in,
                              void* d_out, int out_size, void* d_ws, size_t ws_size,
                              hipStream_t stream) {
    const float* h    = (const float*)d_in[0];
    const float* mem  = (const float*)d_in[1];
    const int*   len  = (const int*)d_in[2];
    const float* Wg_w = (const float*)d_in[3];
    const float* Wg_b = (const float*)d_in[4];
    const float* Ug_w = (const float*)d_in[5];
    const float* Ug_b = (const float*)d_in[6];
    const float* b_g  = (const float*)d_in[7];
    float* out  = (float*)d_out;
    float* r_ws = (float*)d_ws;   // B*D*4 = 8 MiB scratch for r

    attn_kernel<<<BB, 256, 0, stream>>>(h, mem, len, r_ws);
    gate_kernel<<<dim3(BB / 64, DD / 64), 256, 0, stream>>>(
        h, r_ws, len, Wg_w, Wg_b, Ug_w, Ug_b, b_g, out);
}

// Round 4
// 689.726 us; speedup vs baseline: 1.0443x; 1.0443x over previous
//
#include <hip/hip_runtime.h>
#include <hip/hip_bf16.h>

#define BB 8192
#define MM 64
#define DD 256
#define NEGV -1e9f
#define PSTR 68   // part[] row stride in floats

typedef __attribute__((ext_vector_type(8))) short frag_ab;  // 8 bf16 = 4 VGPRs
typedef __attribute__((ext_vector_type(4))) float f32x4;

__device__ inline short f2bs(float f) {
    __hip_bfloat16 v = __float2bfloat16(f);
    return *reinterpret_cast<short*>(&v);
}
__device__ inline float blo(unsigned w) { return __uint_as_float(w << 16); }
__device__ inline float bhi(unsigned w) { return __uint_as_float(w & 0xffff0000u); }

// ---------------------------------------------------------------------------
// Kernel A v4: per-sample masked attention, SKIPPING masked rows' loads.
//   lengths ~ U[0,64] -> on average HALF of mem is masked; masked rows get
//   softmax weight exactly 0, so their loads are pure waste. The predicate
//   (row < L) is wave-uniform -> s_cbranch, no divergence. Avg HBM traffic
//   for mem drops 537 -> ~273 MB.
// ---------------------------------------------------------------------------
__global__ __launch_bounds__(256, 6) void attn_kernel(
    const float* __restrict__ h, const float* __restrict__ mem,
    const int* __restrict__ len, float* __restrict__ r_out)
{
    __shared__ float part[MM * PSTR];              // 17.4 KB [m][lane]
    __shared__ float score_s[MM];
    __shared__ __align__(16) float attn_s[MM];
    __shared__ __align__(16) float rpart[4 * DD];  // 4 KB [wave][d]

    const int b    = blockIdx.x;
    const int t    = threadIdx.x;
    const int lane = t & 63;
    const int wave = t >> 6;
    const int L    = len[b];
    // rows this wave actually needs (wave-uniform)
    const int nrows = min(16, max(0, L - wave * 16));

    const float4 hv = *reinterpret_cast<const float4*>(h + (size_t)b * DD + 4 * lane);
    const float* mbase = mem + (size_t)b * MM * DD + (size_t)(wave * 16) * DD + 4 * lane;

    // ---- phase 1: load only valid rows (coalesced 1KB/row segments),
    //      keep bf16x2 tile in registers; zeros for masked rows.
    unsigned tile[32];
    float p[16];
    #pragma unroll
    for (int i = 0; i < 16; ++i) { tile[2 * i] = 0u; tile[2 * i + 1] = 0u; p[i] = 0.f; }
    #pragma unroll
    for (int i = 0; i < 16; ++i) {
        if (i < nrows) {   // wave-uniform branch
            const float4 v = *reinterpret_cast<const float4*>(mbase + i * DD);
            p[i] = v.x * hv.x + v.y * hv.y + v.z * hv.z + v.w * hv.w;
            __hip_bfloat162 q0 = __float22bfloat162_rn(float2{v.x, v.y});
            __hip_bfloat162 q1 = __float22bfloat162_rn(float2{v.z, v.w});
            tile[2 * i]     = *reinterpret_cast<unsigned*>(&q0);
            tile[2 * i + 1] = *reinterpret_cast<unsigned*>(&q1);
        }
    }
    #pragma unroll
    for (int i = 0; i < 16; ++i)
        part[(wave * 16 + i) * PSTR + lane] = p[i];   // b32, conflict-free
    __syncthreads();

    // ---- phase 2: finish dots: thread -> row m=t>>2, chunk c=t&3
    {
        const int m = t >> 2, c = t & 3;
        const float4* pr = reinterpret_cast<const float4*>(part + m * PSTR + c * 16);
        const float4 s0 = pr[0], s1 = pr[1], s2 = pr[2], s3 = pr[3];
        float s = (s0.x + s0.y + s0.z + s0.w) + (s1.x + s1.y + s1.z + s1.w)
                + (s2.x + s2.y + s2.z + s2.w) + (s3.x + s3.y + s3.z + s3.w);
        s += __shfl_xor(s, 1, 64);
        s += __shfl_xor(s, 2, 64);
        if (c == 0) score_s[m] = (m < L) ? s : NEGV;
    }
    __syncthreads();

    // ---- phase 3: masked softmax over 64 scores (wave 0).
    // L==0: attn uniform but tile==0 -> r = 0 (gate passes h through anyway)
    if (t < 64) {
        const float s = score_s[t];
        float mx = s;
        #pragma unroll
        for (int off = 32; off > 0; off >>= 1)
            mx = fmaxf(mx, __shfl_xor(mx, off, 64));
        const float e = __expf(s - mx);
        float den = e;
        #pragma unroll
        for (int off = 32; off > 0; off >>= 1)
            den += __shfl_xor(den, off, 64);
        attn_s[t] = e / den;
    }
    __syncthreads();

    // ---- phase 4: r partials from the register tile (skip if wave all-masked)
    float4 rp = {0.f, 0.f, 0.f, 0.f};
    if (nrows > 0) {
        #pragma unroll
        for (int ic = 0; ic < 4; ++ic) {
            const float4 aw = *reinterpret_cast<const float4*>(attn_s + wave * 16 + 4 * ic);
            const float a[4] = {aw.x, aw.y, aw.z, aw.w};
            #pragma unroll
            for (int k = 0; k < 4; ++k) {
                const int i = 4 * ic + k;
                rp.x += a[k] * blo(tile[2 * i]);
                rp.y += a[k] * bhi(tile[2 * i]);
                rp.z += a[k] * blo(tile[2 * i + 1]);
                rp.w += a[k] * bhi(tile[2 * i + 1]);
            }
        }
    }
    *reinterpret_cast<float4*>(rpart + wave * DD + 4 * lane) = rp;
    __syncthreads();

    // ---- phase 5: cross-wave sum + store (coalesced)
    const float r = rpart[t] + rpart[DD + t] + rpart[2 * DD + t] + rpart[3 * DD + t];
    r_out[(size_t)b * DD + t] = r;
}

// ---------------------------------------------------------------------------
// Kernel B v3: gating GEMMs + blend, bf16 MFMA 16x16x32, h- and r-phases
//   MERGED into one K-loop (8 iterations, 8 MFMAs/iter, half the barriers).
// ---------------------------------------------------------------------------
__global__ __launch_bounds__(256) void gate_kernel(
    const float* __restrict__ h, const float* __restrict__ r,
    const int* __restrict__ len,
    const float* __restrict__ Wg_w, const float* __restrict__ Wg_b,
    const float* __restrict__ Ug_w, const float* __restrict__ Ug_b,
    const float* __restrict__ b_g, float* __restrict__ out)
{
    __shared__ __hip_bfloat16 Ah[64 * 32];    // 4 KB each, 16 KB total
    __shared__ __hip_bfloat16 Ar[64 * 32];
    __shared__ __hip_bfloat16 Wgs[64 * 32];
    __shared__ __hip_bfloat16 Wus[64 * 32];

    const int t    = threadIdx.x;
    const int lane = t & 63;
    const int wave = t >> 6;
    const int brow0 = blockIdx.x * 64;
    const int dcol0 = blockIdx.y * 64;

    const int srow = t >> 2;     // staging row 0..63
    const int skq  = t & 3;      // staging k-octet

    const f32x4 zero = {0.f, 0.f, 0.f, 0.f};
    f32x4 acc[4];
    #pragma unroll
    for (int ct = 0; ct < 4; ++ct) acc[ct] = zero;

    const int arow_m = (lane & 15);
    const int kchunk = (lane >> 4) * 8;

    const float* hp = h    + (size_t)(brow0 + srow) * DD + skq * 8;
    const float* rp = r    + (size_t)(brow0 + srow) * DD + skq * 8;
    const float* gp = Wg_w + (size_t)(dcol0 + srow) * DD + skq * 8;
    const float* up = Ug_w + (size_t)(dcol0 + srow) * DD + skq * 8;

    for (int k0 = 0; k0 < DD; k0 += 32) {
        const float4 h0 = *reinterpret_cast<const float4*>(hp + k0);
        const float4 h1 = *reinterpret_cast<const float4*>(hp + k0 + 4);
        const float4 r0 = *reinterpret_cast<const float4*>(rp + k0);
        const float4 r1 = *reinterpret_cast<const float4*>(rp + k0 + 4);
        const float4 g0 = *reinterpret_cast<const float4*>(gp + k0);
        const float4 g1 = *reinterpret_cast<const float4*>(gp + k0 + 4);
        const float4 u0 = *reinterpret_cast<const float4*>(up + k0);
        const float4 u1 = *reinterpret_cast<const float4*>(up + k0 + 4);

        __syncthreads();   // previous step's frags fully consumed
        frag_ab fh, fr, fg, fu;
        fh[0]=f2bs(h0.x); fh[1]=f2bs(h0.y); fh[2]=f2bs(h0.z); fh[3]=f2bs(h0.w);
        fh[4]=f2bs(h1.x); fh[5]=f2bs(h1.y); fh[6]=f2bs(h1.z); fh[7]=f2bs(h1.w);
        fr[0]=f2bs(r0.x); fr[1]=f2bs(r0.y); fr[2]=f2bs(r0.z); fr[3]=f2bs(r0.w);
        fr[4]=f2bs(r1.x); fr[5]=f2bs(r1.y); fr[6]=f2bs(r1.z); fr[7]=f2bs(r1.w);
        fg[0]=f2bs(g0.x); fg[1]=f2bs(g0.y); fg[2]=f2bs(g0.z); fg[3]=f2bs(g0.w);
        fg[4]=f2bs(g1.x); fg[5]=f2bs(g1.y); fg[6]=f2bs(g1.z); fg[7]=f2bs(g1.w);
        fu[0]=f2bs(u0.x); fu[1]=f2bs(u0.y); fu[2]=f2bs(u0.z); fu[3]=f2bs(u0.w);
        fu[4]=f2bs(u1.x); fu[5]=f2bs(u1.y); fu[6]=f2bs(u1.z); fu[7]=f2bs(u1.w);
        *reinterpret_cast<frag_ab*>(&Ah [srow * 32 + skq * 8]) = fh;
        *reinterpret_cast<frag_ab*>(&Ar [srow * 32 + skq * 8]) = fr;
        *reinterpret_cast<frag_ab*>(&Wgs[srow * 32 + skq * 8]) = fg;
        *reinterpret_cast<frag_ab*>(&Wus[srow * 32 + skq * 8]) = fu;
        __syncthreads();

        const frag_ab afh = *reinterpret_cast<const frag_ab*>(
            &Ah[(wave * 16 + arow_m) * 32 + kchunk]);
        const frag_ab afr = *reinterpret_cast<const frag_ab*>(
            &Ar[(wave * 16 + arow_m) * 32 + kchunk]);
        #pragma unroll
        for (int ct = 0; ct < 4; ++ct) {
            const frag_ab wfg = *reinterpret_cast<const frag_ab*>(
                &Wgs[(ct * 16 + arow_m) * 32 + kchunk]);
            const frag_ab wfu = *reinterpret_cast<const frag_ab*>(
                &Wus[(ct * 16 + arow_m) * 32 + kchunk]);
            acc[ct] = __builtin_amdgcn_mfma_f32_16x16x32_bf16(afh, wfg, acc[ct], 0, 0, 0);
            acc[ct] = __builtin_amdgcn_mfma_f32_16x16x32_bf16(afr, wfu, acc[ct], 0, 0, 0);
        }
    }

    // epilogue: bias + sigmoid + blend + empty-memory passthrough
    // C/D layout: col = lane&15, row = (lane>>4)*4 + reg
    float bias_v[4];
    #pragma unroll
    for (int ct = 0; ct < 4; ++ct) {
        const int d = dcol0 + ct * 16 + (lane & 15);
        bias_v[ct] = Wg_b[d] + Ug_b[d] + b_g[d];
    }
    const int rbase = brow0 + wave * 16 + (lane >> 4) * 4;
    #pragma unroll
    for (int i = 0; i < 4; ++i) {
        const int bb = rbase + i;
        const int lb = len[bb];
        #pragma unroll
        for (int ct = 0; ct < 4; ++ct) {
            const int d = dcol0 + ct * 16 + (lane & 15);
            const float x = acc[ct][i] + bias_v[ct];
            const float g = 1.f / (1.f + __expf(-x));
            const size_t idx = (size_t)bb * DD + d;
            const float rv = r[idx];
            const float hvv = h[idx];
            out[idx] = (lb > 0) ? (hvv + g * (rv - hvv)) : hvv;
        }
    }
}

extern "C" void kernel_launch(void* const* d_in, const int* in_sizes, int n_in,
                              void* d_out, int out_size, void* d_ws, size_t ws_size,
                              hipStream_t stream) {
    const float* h    = (const float*)d_in[0];
    const float* mem  = (const float*)d_in[1];
    const int*   len  = (const int*)d_in[2];
    const float* Wg_w = (const float*)d_in[3];
    const float* Wg_b = (const float*)d_in[4];
    const float* Ug_w = (const float*)d_in[5];
    const float* Ug_b = (const float*)d_in[6];
    const float* b_g  = (const float*)d_in[7];
    float* out  = (float*)d_out;
    float* r_ws = (float*)d_ws;   // B*D*4 = 8 MiB scratch for r

    attn_kernel<<<BB, 256, 0, stream>>>(h, mem, len, r_ws);
    gate_kernel<<<dim3(BB / 64, DD / 64), 256, 0, stream>>>(
        h, r_ws, len, Wg_w, Wg_b, Ug_w, Ug_b, b_g, out);
}